// Round 11
// baseline (29.773 us; speedup 1.0000x reference)
//
#include <hip/hip_runtime.h>
#include <cstdint>
#include <cstddef>

#define BS 8
#define NQ 16384
#define NG 1024
#define NC 5
#define BPB 32              // blocks per batch -> grid 256 = 1 block/CU
#define WCAP 704            // per-wave stage-1 region (16*704*4 = 45056 B)
#define CAP 448             // per-class exact candidate list (5*448*8 = 17920 B)
#define PREF 0.55f          // static argmax-prob prefilter (> 0.5!)
#define SLACK 0.1514214f    // 0.1*sqrt(2) + 0.01 margin
#define B2EPS 1e-3f         // quantization/fast-math slop on the list filter

using u64 = unsigned long long;
typedef unsigned int u32;

// ---------- u64 keyed top-4 (exact, tie-break by low 32 = q) ----------
__device__ __forceinline__ void ce(u64 &x, u64 &y) {
    u64 lo = x < y ? x : y;
    u64 hi = x < y ? y : x;
    x = lo; y = hi;
}
__device__ __forceinline__ void merge4(u64 a[4], u64 b0, u64 b1, u64 b2, u64 b3) {
    u64 m0 = a[0] < b3 ? a[0] : b3;
    u64 m1 = a[1] < b2 ? a[1] : b2;
    u64 m2 = a[2] < b1 ? a[2] : b1;
    u64 m3 = a[3] < b0 ? a[3] : b0;
    ce(m0, m2); ce(m1, m3); ce(m0, m1); ce(m2, m3);
    a[0] = m0; a[1] = m1; a[2] = m2; a[3] = m3;
}
__device__ __forceinline__ void kinsert(u64 kk[4], float cost, unsigned q) {
    unsigned uu = __float_as_uint(cost);
    uu ^= ((unsigned)((int)uu >> 31)) | 0x80000000u;
    u64 k = ((u64)uu << 32) | q;
    if (k < kk[3]) { kk[3] = k; ce(kk[2], kk[3]); ce(kk[1], kk[2]); ce(kk[0], kk[1]); }
}

// ---------- u32 descending top-4 ----------
__device__ __forceinline__ u32 umaxu(u32 a, u32 b) { return a > b ? a : b; }
__device__ __forceinline__ u32 uminu(u32 a, u32 b) { return a < b ? a : b; }
__device__ __forceinline__ void uce_desc(u32 &x, u32 &y) {
    u32 hi = umaxu(x, y), lo = uminu(x, y); x = hi; y = lo;
}
__device__ __forceinline__ void uinsert_desc(u32 k[4], u32 v) {
    u32 t;
    t = umaxu(k[0], v); v = uminu(k[0], v); k[0] = t;
    t = umaxu(k[1], v); v = uminu(k[1], v); k[1] = t;
    t = umaxu(k[2], v); v = uminu(k[2], v); k[2] = t;
    k[3] = umaxu(k[3], v);
}
__device__ __forceinline__ void umerge4_desc(u32 a[4], u32 b0, u32 b1, u32 b2, u32 b3) {
    u32 m0 = umaxu(a[0], b3), m1 = umaxu(a[1], b2), m2 = umaxu(a[2], b1), m3 = umaxu(a[3], b0);
    uce_desc(m0, m2); uce_desc(m1, m3); uce_desc(m0, m1); uce_desc(m2, m3);
    a[0] = m0; a[1] = m1; a[2] = m2; a[3] = m3;
}

// exact softmax numerics — identical to all prior passing rounds
#define SOFTMAX5(lg, X0, X1, X2, X3, X4, S)                                     \
    float X0 = (lg)[0], X1 = (lg)[1], X2 = (lg)[2], X3 = (lg)[3], X4 = (lg)[4]; \
    {                                                                           \
        float mx_ = fmaxf(fmaxf(fmaxf(X0, X1), fmaxf(X2, X3)), X4);             \
        X0 = expf(X0 - mx_); X1 = expf(X1 - mx_); X2 = expf(X2 - mx_);          \
        X3 = expf(X3 - mx_); X4 = expf(X4 - mx_);                               \
    }                                                                           \
    float S = X0 + X1 + X2 + X3 + X4;

// fast argmax prob + class (rcp err ~3e-6, inside SLACK/B2EPS margins)
#define PSTAR(L0, L1, L2, L3, L4, PS, CS)                                       \
    float PS; int CS;                                                           \
    {                                                                           \
        float m_ = fmaxf(fmaxf(fmaxf(L0, L1), fmaxf(L2, L3)), L4);              \
        float e0_ = __expf(L0 - m_), e1_ = __expf(L1 - m_), e2_ = __expf(L2 - m_); \
        float e3_ = __expf(L3 - m_), e4_ = __expf(L4 - m_);                     \
        PS = __builtin_amdgcn_rcpf(((e0_ + e1_) + (e2_ + e3_)) + e4_);          \
        CS = (L4 == m_) ? 4 : (L3 == m_) ? 3 : (L2 == m_) ? 2 : (L1 == m_) ? 1 : 0; \
    }

// Single-pass argmax prune, per-wave regions (no pass-1 atomics):
//  P1: 4 q/thread/iter via 5x float4; append (p15,c*,q) keys to the wave's
//      own L region with a register counter when p* >= PREF.
//  A2: each wave builds 5 class-top-4s over its own region; 16-way LDS merge
//      -> T_c = P4_est - SLACK. Flags -> exact brute per class when: any
//      region overflow, class count < 4, or T_c < PREF + eps.
//  B2: each wave refilters its region (+B2EPS slop); accepted get EXACT p
//      (expf + x/s, bit-identical to prior rounds) into lists[c].
//  C : exact keyed top-4 per gt over lists[c] (or brute if flagged).
// Prune validity: p_c >= T_c > 0.5 => c is q's unique argmax and
// p*_fast >= p_c - 3e-6 >= PREF (flag guards the boundary) => q is in L.
__global__ __launch_bounds__(1024, 1) void fused_kernel(
        const float* __restrict__ pred_coords,   // [BS][NQ][2]
        const float* __restrict__ logits,        // [BS][NQ][NC]
        const float* __restrict__ gt_coords,     // [BS][NG][2]
        const int*   __restrict__ gt_labels,     // [BS][NG]
        const int*   __restrict__ gt_masks,      // [BS][NG]
        int*         __restrict__ out)           // [BS][4][NG]
{
    const int tid = threadIdx.x;
    const int wv = tid >> 6, lane = tid & 63;    // 16 waves
    const int b = blockIdx.x / BPB, part = blockIdx.x % BPB;
    const u64 lmlt = (1ull << lane) - 1ull;

    __shared__ u64  lists[NC][CAP];              // 17920 B (8B-aligned first)
    __shared__ u32  L[16][WCAP];                 // 45056 B
    __shared__ u32  a2buf[16][NC][4];
    __shared__ u32  a2cnt[16][NC];
    __shared__ float Tsh[NC];
    __shared__ u32  lcount[NC];
    __shared__ u32  flags;

    if (tid == 0) flags = 0u;
    if (tid < NC) lcount[tid] = 0u;
    __syncthreads();

    const float* lgb = logits + (size_t)b * NQ * NC;
    u32* Lw = L[wv];
    u32 mycnt = 0u;                              // wave-uniform register counter

    // ---------------- pass 1: single scan, 4 q per thread-iter ----------------
    #pragma unroll 2
    for (int r = 0; r < 4; ++r) {
        int qb = r * 4096 + tid * 4;             // 4 consecutive queries
        const float4* pv = reinterpret_cast<const float4*>(lgb + (size_t)qb * NC);
        float4 v0 = pv[0], v1 = pv[1], v2 = pv[2], v3 = pv[3], v4 = pv[4];
        PSTAR(v0.x, v0.y, v0.z, v0.w, v1.x, psA, csA);
        PSTAR(v1.y, v1.z, v1.w, v2.x, v2.y, psB, csB);
        PSTAR(v2.z, v2.w, v3.x, v3.y, v3.z, psC, csC);
        PSTAR(v3.w, v4.x, v4.y, v4.z, v4.w, psD, csD);
        #define APP(PS, CS, QQ)                                                     \
        {                                                                           \
            bool pass = ((PS) >= PREF);                                             \
            u64 mk = __ballot(pass);                                                \
            if (mk) {                                                               \
                if (pass) {                                                         \
                    u32 fb = __float_as_uint(PS);                                   \
                    fb = fb > 0x3F7FFFFFu ? 0x3F7FFFFFu : fb;                       \
                    u32 key = (((fb >> 8) & 0x7FFFu) << 17) | ((u32)(CS) << 14) | (u32)(QQ); \
                    u32 slot = mycnt + (u32)__popcll(mk & lmlt);                    \
                    if (slot < WCAP) Lw[slot] = key;                                \
                }                                                                   \
                mycnt += (u32)__popcll(mk);                                         \
            }                                                                       \
        }
        APP(psA, csA, qb + 0)
        APP(psB, csB, qb + 1)
        APP(psC, csC, qb + 2)
        APP(psD, csD, qb + 3)
        #undef APP
    }
    if (lane == 0 && mycnt > WCAP) atomicOr(&flags, 0x1Fu);   // region overflow -> all brute
    const u32 nW = mycnt < WCAP ? mycnt : WCAP;

    // ---------------- A2a: per-wave 5-class top-4 over own region ----------------
    {
        u32 t40[4] = {0u,0u,0u,0u}, t41[4] = {0u,0u,0u,0u}, t42[4] = {0u,0u,0u,0u};
        u32 t43[4] = {0u,0u,0u,0u}, t44[4] = {0u,0u,0u,0u};
        u32 c0 = 0u, c1 = 0u, c2 = 0u, c3 = 0u, c4 = 0u;
        for (u32 j = (u32)lane; j < nW; j += 64u) {
            u32 k = Lw[j];
            u32 c = (k >> 14) & 7u;
            uinsert_desc(t40, c == 0u ? k : 0u); c0 += (c == 0u);
            uinsert_desc(t41, c == 1u ? k : 0u); c1 += (c == 1u);
            uinsert_desc(t42, c == 2u ? k : 0u); c2 += (c == 2u);
            uinsert_desc(t43, c == 3u ? k : 0u); c3 += (c == 3u);
            uinsert_desc(t44, c == 4u ? k : 0u); c4 += (c == 4u);
        }
        #pragma unroll
        for (int d = 1; d < 64; d <<= 1) {
            #define RED(T, C)                                                       \
                umerge4_desc(T, (u32)__shfl_xor((int)T[0], d, 64),                  \
                                (u32)__shfl_xor((int)T[1], d, 64),                  \
                                (u32)__shfl_xor((int)T[2], d, 64),                  \
                                (u32)__shfl_xor((int)T[3], d, 64));                 \
                C += (u32)__shfl_xor((int)C, d, 64);
            RED(t40, c0) RED(t41, c1) RED(t42, c2) RED(t43, c3) RED(t44, c4)
            #undef RED
        }
        if (lane == 0) {
            #define ST(I, T, C)                                                     \
                a2buf[wv][I][0] = T[0]; a2buf[wv][I][1] = T[1];                     \
                a2buf[wv][I][2] = T[2]; a2buf[wv][I][3] = T[3]; a2cnt[wv][I] = C;
            ST(0, t40, c0) ST(1, t41, c1) ST(2, t42, c2) ST(3, t43, c3) ST(4, t44, c4)
            #undef ST
        }
    }
    __syncthreads();

    // ---------------- A2b: final per-class threshold ----------------
    if (tid < NC) {
        u32 t4[4] = {a2buf[0][tid][0], a2buf[0][tid][1], a2buf[0][tid][2], a2buf[0][tid][3]};
        u32 cnt = a2cnt[0][tid];
        #pragma unroll
        for (int w = 1; w < 16; ++w) {
            umerge4_desc(t4, a2buf[w][tid][0], a2buf[w][tid][1], a2buf[w][tid][2], a2buf[w][tid][3]);
            cnt += a2cnt[w][tid];
        }
        float p4 = __uint_as_float(0x3F000000u | ((t4[3] >> 17) << 8));  // <= true P4*
        float T = p4 - SLACK;
        Tsh[tid] = T;
        if (cnt < 4u || T < PREF + 1e-5f) atomicOr(&flags, 1u << tid);
    }
    __syncthreads();

    // ---------------- B2: refilter own region; exact p for accepted ----------------
    {
        u32 fl = flags;
        for (u32 j = (u32)lane; j < nW; j += 64u) {
            u32 k = Lw[j];
            u32 c = (k >> 14) & 7u;
            if ((fl >> c) & 1u) continue;
            float pf = __uint_as_float(0x3F000000u | ((k >> 17) << 8));
            if (pf >= Tsh[c] - B2EPS) {
                u32 q = k & 0x3FFFu;
                const float* lg = lgb + (size_t)q * NC;
                SOFTMAX5(lg, x0, x1, x2, x3, x4, s);
                float num = (c == 0) ? x0 : (c == 1) ? x1 : (c == 2) ? x2 : (c == 3) ? x3 : x4;
                float pe = num / s;              // exact numerics (matches prior rounds)
                u32 slot = atomicAdd(&lcount[c], 1u);
                if (slot < CAP) lists[c][slot] = ((u64)__float_as_uint(pe) << 32) | q;
            }
        }
    }
    __syncthreads();
    if (tid < NC && lcount[tid] > CAP) atomicOr(&flags, 1u << tid);
    __syncthreads();

    // ---------------- phase C: exact keyed top-4 per gt (2 gts/wave) ----------------
    const float2* pc = reinterpret_cast<const float2*>(pred_coords) + (size_t)b * NQ;
    const u32 fl2 = flags;
    #pragma unroll 1
    for (int i = 0; i < 2; ++i) {
        int g = part * (NG / BPB) + i * 16 + wv;
        int m = gt_masks[b * NG + g];
        u64 kk[4] = {~0ull, ~0ull, ~0ull, ~0ull};
        if (m) {
            int c = gt_labels[b * NG + g];
            float2 gc = reinterpret_cast<const float2*>(gt_coords)[(size_t)b * NG + g];
            float gx = gc.x, gy = gc.y, gb2 = gc.x * gc.x + gc.y * gc.y;
            if (!((fl2 >> c) & 1u)) {
                u32 nn = lcount[c] < CAP ? lcount[c] : CAP;
                for (u32 j = (u32)lane; j < nn; j += 64u) {
                    u64 e = lists[c][j];
                    float p = __uint_as_float((unsigned)(e >> 32));
                    unsigned qq = (unsigned)(e & 0xFFFFFFFFu);
                    float2 cq = pc[qq];
                    float d2 = fmaxf(cq.x * cq.x + cq.y * cq.y + gb2
                                     - 2.0f * (cq.x * gx + cq.y * gy), 0.0f);
                    kinsert(kk, 0.1f * sqrtf(d2) - p, qq);
                }
            } else {
                // flagged class: exact brute scan (same numerics, always correct)
                for (int q2 = lane; q2 < NQ; q2 += 64) {
                    const float* lg2 = lgb + (size_t)q2 * NC;
                    SOFTMAX5(lg2, y0, y1, y2, y3, y4, s2);
                    float num = (c == 0) ? y0 : (c == 1) ? y1 : (c == 2) ? y2 : (c == 3) ? y3 : y4;
                    float p = num / s2;
                    float2 cq = pc[q2];
                    float d2 = fmaxf(cq.x * cq.x + cq.y * cq.y + gb2
                                     - 2.0f * (cq.x * gx + cq.y * gy), 0.0f);
                    kinsert(kk, 0.1f * sqrtf(d2) - p, (unsigned)q2);
                }
            }
            #pragma unroll
            for (int d = 1; d < 64; d <<= 1) {
                u64 b0 = __shfl_xor(kk[0], d, 64);
                u64 b1 = __shfl_xor(kk[1], d, 64);
                u64 b2_ = __shfl_xor(kk[2], d, 64);
                u64 b3 = __shfl_xor(kk[3], d, 64);
                merge4(kk, b0, b1, b2_, b3);
            }
        }
        if (lane < 4) {
            u64 sel = (lane == 0) ? kk[0] : (lane == 1) ? kk[1] : (lane == 2) ? kk[2] : kk[3];
            int idx = m ? (int)(sel & 0xFFFFFFFFull) : lane;
            out[((size_t)(b * 4 + lane) << 10) + g] = idx;
        }
    }
}

extern "C" void kernel_launch(void* const* d_in, const int* in_sizes, int n_in,
                              void* d_out, int out_size, void* d_ws, size_t ws_size,
                              hipStream_t stream) {
    const float* pred_coords = (const float*)d_in[0];
    const float* pred_logits = (const float*)d_in[1];
    const float* gt_coords   = (const float*)d_in[2];
    const int*   gt_labels   = (const int*)d_in[3];
    const int*   gt_masks    = (const int*)d_in[4];
    int* out = (int*)d_out;

    fused_kernel<<<BS * BPB, 1024, 0, stream>>>(
        pred_coords, pred_logits, gt_coords, gt_labels, gt_masks, out);
}

// Round 12
// 28.874 us; speedup vs baseline: 1.0311x; 1.0311x over previous
//
#include <hip/hip_runtime.h>
#include <cstdint>
#include <cstddef>

#define BS 8
#define NQ 16384
#define NG 1024
#define NC 5
#define BPB 32              // blocks per batch -> grid 256 = 1 block/CU
#define WCAP 704            // per-wave stage-1 region (16*704*4 = 45056 B)
#define CAP 448             // per-class exact candidate list (5*448*8 = 17920 B)
#define PREF 0.55f          // argmax-prob prefilter (> 0.5!)
#define SMAXG 1.8185f       // s-domain gate: 1/PREF with +3e-4 safety slop
#define SLACK 0.1514214f    // 0.1*sqrt(2) + 0.01 margin
#define B2EPS 1e-3f         // slop on the list filter (>> quant step 1.2e-4)

using u64 = unsigned long long;
typedef unsigned int u32;

// ---------- u64 keyed top-4 (exact, tie-break by low 32 = q) ----------
__device__ __forceinline__ void ce(u64 &x, u64 &y) {
    u64 lo = x < y ? x : y;
    u64 hi = x < y ? y : x;
    x = lo; y = hi;
}
__device__ __forceinline__ void merge4(u64 a[4], u64 b0, u64 b1, u64 b2, u64 b3) {
    u64 m0 = a[0] < b3 ? a[0] : b3;
    u64 m1 = a[1] < b2 ? a[1] : b2;
    u64 m2 = a[2] < b1 ? a[2] : b1;
    u64 m3 = a[3] < b0 ? a[3] : b0;
    ce(m0, m2); ce(m1, m3); ce(m0, m1); ce(m2, m3);
    a[0] = m0; a[1] = m1; a[2] = m2; a[3] = m3;
}
__device__ __forceinline__ void kinsert(u64 kk[4], float cost, unsigned q) {
    unsigned uu = __float_as_uint(cost);
    uu ^= ((unsigned)((int)uu >> 31)) | 0x80000000u;
    u64 k = ((u64)uu << 32) | q;
    if (k < kk[3]) { kk[3] = k; ce(kk[2], kk[3]); ce(kk[1], kk[2]); ce(kk[0], kk[1]); }
}

// ---------- u32 descending top-4 ----------
__device__ __forceinline__ u32 umaxu(u32 a, u32 b) { return a > b ? a : b; }
__device__ __forceinline__ u32 uminu(u32 a, u32 b) { return a < b ? a : b; }
__device__ __forceinline__ void uce_desc(u32 &x, u32 &y) {
    u32 hi = umaxu(x, y), lo = uminu(x, y); x = hi; y = lo;
}
__device__ __forceinline__ void uinsert_desc(u32 k[4], u32 v) {
    u32 t;
    t = umaxu(k[0], v); v = uminu(k[0], v); k[0] = t;
    t = umaxu(k[1], v); v = uminu(k[1], v); k[1] = t;
    t = umaxu(k[2], v); v = uminu(k[2], v); k[2] = t;
    k[3] = umaxu(k[3], v);
}
__device__ __forceinline__ void umerge4_desc(u32 a[4], u32 b0, u32 b1, u32 b2, u32 b3) {
    u32 m0 = umaxu(a[0], b3), m1 = umaxu(a[1], b2), m2 = umaxu(a[2], b1), m3 = umaxu(a[3], b0);
    uce_desc(m0, m2); uce_desc(m1, m3); uce_desc(m0, m1); uce_desc(m2, m3);
    a[0] = m0; a[1] = m1; a[2] = m2; a[3] = m3;
}

// exact softmax numerics — identical to all prior passing rounds
#define SOFTMAX5(lg, X0, X1, X2, X3, X4, S)                                     \
    float X0 = (lg)[0], X1 = (lg)[1], X2 = (lg)[2], X3 = (lg)[3], X4 = (lg)[4]; \
    {                                                                           \
        float mx_ = fmaxf(fmaxf(fmaxf(X0, X1), fmaxf(X2, X3)), X4);             \
        X0 = expf(X0 - mx_); X1 = expf(X1 - mx_); X2 = expf(X2 - mx_);          \
        X3 = expf(X3 - mx_); X4 = expf(X4 - mx_);                               \
    }                                                                           \
    float S = X0 + X1 + X2 + X3 + X4;

// fast scan: s = sum(exp(li-m)) (p* = 1/s implicit; no rcp needed) + argmax class
#define PSCAN(L0, L1, L2, L3, L4, SS, CS)                                       \
    float SS; int CS;                                                           \
    {                                                                           \
        float m01_ = fmaxf(L0, L1), m23_ = fmaxf(L2, L3);                       \
        float mA_ = fmaxf(m01_, m23_);                                          \
        float m_ = fmaxf(mA_, L4);                                              \
        int cA_ = (m23_ > m01_) ? ((L3 > L2) ? 3 : 2) : ((L1 > L0) ? 1 : 0);    \
        CS = (L4 > mA_) ? 4 : cA_;                                              \
        float e0_ = __expf(L0 - m_), e1_ = __expf(L1 - m_), e2_ = __expf(L2 - m_); \
        float e3_ = __expf(L3 - m_), e4_ = __expf(L4 - m_);                     \
        SS = ((e0_ + e1_) + (e2_ + e3_)) + e4_;                                 \
    }

// Single-pass argmax prune, s-domain keys, per-wave regions:
//  P1: 16 q/thread (full unroll, 20 hoisted float4 loads); gate s <= SMAXG;
//      append key = (squant15, c*, q) to wave's own region (reg counter).
//      Key order: descending key = ascending s = descending p*.
//  A2a: per-wave 5-class top-4 keys; 16-way LDS merge.
//  A2b (once/class): s_ub = dequant+1 quantum -> p4_lb = 1/s_ub (precise);
//      T_c = p4_lb - SLACK; flag if T_c < PREF+1e-5 (covers <4-candidates
//      case: zero keys decode to p4~0.06). KMIN_c = quant(1/(T_c-B2EPS))-1.
//  B2: integer filter kq >= KMIN_c; accepted get EXACT p (expf + x/s,
//      bit-identical to prior rounds) into lists[c]. Overflow -> flag.
//  C : exact keyed top-4 per gt over lists[c] (brute scan if flagged).
// Conservative chain: p_exact>=T_c>0.5 => c unique argmax, s_fast <=
// (1+4e-6)/T_c < dequant(KMIN_c) and <= SMAXG; quant step (~1.2e-4 in p)
// + fast-math (4e-6) one-sided inside B2EPS=1e-3 and SLACK's 0.01 spare.
__global__ __launch_bounds__(1024, 1) void fused_kernel(
        const float* __restrict__ pred_coords,   // [BS][NQ][2]
        const float* __restrict__ logits,        // [BS][NQ][NC]
        const float* __restrict__ gt_coords,     // [BS][NG][2]
        const int*   __restrict__ gt_labels,     // [BS][NG]
        const int*   __restrict__ gt_masks,      // [BS][NG]
        int*         __restrict__ out)           // [BS][4][NG]
{
    const int tid = threadIdx.x;
    const int wv = tid >> 6, lane = tid & 63;    // 16 waves
    const int b = blockIdx.x / BPB, part = blockIdx.x % BPB;
    const u64 lmlt = (1ull << lane) - 1ull;

    __shared__ u64  lists[NC][CAP];              // 17920 B (8B-aligned first)
    __shared__ u32  L[16][WCAP];                 // 45056 B
    __shared__ u32  a2buf[16][NC][4];
    __shared__ u32  KMIN[NC];
    __shared__ u32  lcount[NC];
    __shared__ u32  flags;

    if (tid == 0) flags = 0u;
    if (tid < NC) lcount[tid] = 0u;
    // (no barrier: consumed only after the A2a barrier below)

    const float* lgb = logits + (size_t)b * NQ * NC;
    u32* Lw = L[wv];
    u32 mycnt = 0u;                              // wave-uniform register counter

    // ---------------- pass 1: single scan, 16 q/thread, full unroll ----------------
    #pragma unroll
    for (int r = 0; r < 4; ++r) {
        int qb = r * 4096 + tid * 4;             // 4 consecutive queries
        const float4* pv = reinterpret_cast<const float4*>(lgb + (size_t)qb * NC);
        float4 v0 = pv[0], v1 = pv[1], v2 = pv[2], v3 = pv[3], v4 = pv[4];
        PSCAN(v0.x, v0.y, v0.z, v0.w, v1.x, sA, csA);
        PSCAN(v1.y, v1.z, v1.w, v2.x, v2.y, sB, csB);
        PSCAN(v2.z, v2.w, v3.x, v3.y, v3.z, sC, csC);
        PSCAN(v3.w, v4.x, v4.y, v4.z, v4.w, sD, csD);
        #define APP(SS, CS, QQ)                                                     \
        {                                                                           \
            bool pass = ((SS) <= SMAXG);                                            \
            u64 mk = __ballot(pass);                                                \
            if (mk) {                                                               \
                if (pass) {                                                         \
                    u32 sq = (__float_as_uint(SS) - 0x3F800000u) >> 10;             \
                    u32 key = ((0x7FFFu - sq) << 17) | ((u32)(CS) << 14) | (u32)(QQ); \
                    u32 slot = mycnt + (u32)__popcll(mk & lmlt);                    \
                    if (slot < WCAP) Lw[slot] = key;                                \
                }                                                                   \
                mycnt += (u32)__popcll(mk);                                         \
            }                                                                       \
        }
        APP(sA, csA, qb + 0)
        APP(sB, csB, qb + 1)
        APP(sC, csC, qb + 2)
        APP(sD, csD, qb + 3)
        #undef APP
    }
    if (lane == 0 && mycnt > WCAP) atomicOr(&flags, 0x1Fu);   // region overflow -> all brute
    const u32 nW = mycnt < WCAP ? mycnt : WCAP;

    // ---------------- A2a: per-wave 5-class top-4 over own region ----------------
    {
        u32 t40[4] = {0u,0u,0u,0u}, t41[4] = {0u,0u,0u,0u}, t42[4] = {0u,0u,0u,0u};
        u32 t43[4] = {0u,0u,0u,0u}, t44[4] = {0u,0u,0u,0u};
        for (u32 j = (u32)lane; j < nW; j += 64u) {
            u32 k = Lw[j];
            u32 c = (k >> 14) & 7u;
            uinsert_desc(t40, c == 0u ? k : 0u);
            uinsert_desc(t41, c == 1u ? k : 0u);
            uinsert_desc(t42, c == 2u ? k : 0u);
            uinsert_desc(t43, c == 3u ? k : 0u);
            uinsert_desc(t44, c == 4u ? k : 0u);
        }
        #pragma unroll
        for (int d = 1; d < 64; d <<= 1) {
            #define RED(T)                                                          \
                umerge4_desc(T, (u32)__shfl_xor((int)T[0], d, 64),                  \
                                (u32)__shfl_xor((int)T[1], d, 64),                  \
                                (u32)__shfl_xor((int)T[2], d, 64),                  \
                                (u32)__shfl_xor((int)T[3], d, 64));
            RED(t40) RED(t41) RED(t42) RED(t43) RED(t44)
            #undef RED
        }
        if (lane == 0) {
            #define ST(I, T)                                                        \
                a2buf[wv][I][0] = T[0]; a2buf[wv][I][1] = T[1];                     \
                a2buf[wv][I][2] = T[2]; a2buf[wv][I][3] = T[3];
            ST(0, t40) ST(1, t41) ST(2, t42) ST(3, t43) ST(4, t44)
            #undef ST
        }
    }
    __syncthreads();

    // ---------------- A2b: per-class threshold -> integer cutoff ----------------
    if (tid < NC) {
        u32 t4[4] = {a2buf[0][tid][0], a2buf[0][tid][1], a2buf[0][tid][2], a2buf[0][tid][3]};
        #pragma unroll
        for (int w = 1; w < 16; ++w)
            umerge4_desc(t4, a2buf[w][tid][0], a2buf[w][tid][1], a2buf[w][tid][2], a2buf[w][tid][3]);
        u32 q15 = t4[3] >> 17;
        float s_ub = __uint_as_float(0x3F800000u + ((0x7FFFu - q15 + 1u) << 10));
        float p4 = 1.0f / s_ub;                  // <= true P4* (precise div, once)
        float T = p4 - SLACK;
        if (T < PREF + 1e-5f) {
            atomicOr(&flags, 1u << tid);
            KMIN[tid] = 0xFFFFFFFFu;             // nothing passes B2 for this class
        } else {
            float s_cut = 1.0f / (T - B2EPS);    // precise div, once
            u32 kmin = 0x7FFFu - ((__float_as_uint(s_cut) - 0x3F800000u) >> 10);
            KMIN[tid] = (kmin >= 1u) ? (kmin - 1u) : 0u;   // one-quantum pad
        }
    }
    __syncthreads();

    // ---------------- B2: integer refilter own region; exact p for accepted ----------------
    for (u32 j = (u32)lane; j < nW; j += 64u) {
        u32 k = Lw[j];
        u32 c = (k >> 14) & 7u;
        if ((k >> 17) >= KMIN[c]) {
            u32 q = k & 0x3FFFu;
            const float* lg = lgb + (size_t)q * NC;
            SOFTMAX5(lg, x0, x1, x2, x3, x4, s);
            float num = (c == 0) ? x0 : (c == 1) ? x1 : (c == 2) ? x2 : (c == 3) ? x3 : x4;
            float pe = num / s;                  // exact numerics (matches prior rounds)
            u32 slot = atomicAdd(&lcount[c], 1u);
            if (slot < CAP) lists[c][slot] = ((u64)__float_as_uint(pe) << 32) | q;
        }
    }
    __syncthreads();
    if (tid < NC && lcount[tid] > CAP) atomicOr(&flags, 1u << tid);
    __syncthreads();

    // ---------------- phase C: exact keyed top-4 per gt (2 gts/wave) ----------------
    const float2* pc = reinterpret_cast<const float2*>(pred_coords) + (size_t)b * NQ;
    const u32 fl2 = flags;
    #pragma unroll 1
    for (int i = 0; i < 2; ++i) {
        int g = part * (NG / BPB) + i * 16 + wv;
        int m = gt_masks[b * NG + g];
        u64 kk[4] = {~0ull, ~0ull, ~0ull, ~0ull};
        if (m) {
            int c = gt_labels[b * NG + g];
            float2 gc = reinterpret_cast<const float2*>(gt_coords)[(size_t)b * NG + g];
            float gx = gc.x, gy = gc.y, gb2 = gc.x * gc.x + gc.y * gc.y;
            if (!((fl2 >> c) & 1u)) {
                u32 nn = lcount[c] < CAP ? lcount[c] : CAP;
                for (u32 j = (u32)lane; j < nn; j += 64u) {
                    u64 e = lists[c][j];
                    float p = __uint_as_float((unsigned)(e >> 32));
                    unsigned qq = (unsigned)(e & 0xFFFFFFFFu);
                    float2 cq = pc[qq];
                    float d2 = fmaxf(cq.x * cq.x + cq.y * cq.y + gb2
                                     - 2.0f * (cq.x * gx + cq.y * gy), 0.0f);
                    kinsert(kk, 0.1f * sqrtf(d2) - p, qq);
                }
            } else {
                // flagged class: exact brute scan (same numerics, always correct)
                for (int q2 = lane; q2 < NQ; q2 += 64) {
                    const float* lg2 = lgb + (size_t)q2 * NC;
                    SOFTMAX5(lg2, y0, y1, y2, y3, y4, s2);
                    float num = (c == 0) ? y0 : (c == 1) ? y1 : (c == 2) ? y2 : (c == 3) ? y3 : y4;
                    float p = num / s2;
                    float2 cq = pc[q2];
                    float d2 = fmaxf(cq.x * cq.x + cq.y * cq.y + gb2
                                     - 2.0f * (cq.x * gx + cq.y * gy), 0.0f);
                    kinsert(kk, 0.1f * sqrtf(d2) - p, (unsigned)q2);
                }
            }
            #pragma unroll
            for (int d = 1; d < 64; d <<= 1) {
                u64 b0 = __shfl_xor(kk[0], d, 64);
                u64 b1 = __shfl_xor(kk[1], d, 64);
                u64 b2_ = __shfl_xor(kk[2], d, 64);
                u64 b3 = __shfl_xor(kk[3], d, 64);
                merge4(kk, b0, b1, b2_, b3);
            }
        }
        if (lane < 4) {
            u64 sel = (lane == 0) ? kk[0] : (lane == 1) ? kk[1] : (lane == 2) ? kk[2] : kk[3];
            int idx = m ? (int)(sel & 0xFFFFFFFFull) : lane;
            out[((size_t)(b * 4 + lane) << 10) + g] = idx;
        }
    }
}

extern "C" void kernel_launch(void* const* d_in, const int* in_sizes, int n_in,
                              void* d_out, int out_size, void* d_ws, size_t ws_size,
                              hipStream_t stream) {
    const float* pred_coords = (const float*)d_in[0];
    const float* pred_logits = (const float*)d_in[1];
    const float* gt_coords   = (const float*)d_in[2];
    const int*   gt_labels   = (const int*)d_in[3];
    const int*   gt_masks    = (const int*)d_in[4];
    int* out = (int*)d_out;

    fused_kernel<<<BS * BPB, 1024, 0, stream>>>(
        pred_coords, pred_logits, gt_coords, gt_labels, gt_masks, out);
}